// Round 1
// 294.295 us; speedup vs baseline: 2.2881x; 2.2881x over previous
//
#include <hip/hip_runtime.h>

// patches_generator: bilinear grid_sample (border, align_corners=False)
// fm:   [N=16, C=128, H=112, W=112] f32
// grid: [N, P=98, 16, 16, 2] f32  (x,y) in [-1,1]
// out:  [N, P, C, 16, 16] f32
//
// Strategy: one block per (n, c) feature plane. Stage the 49 KB plane into
// LDS with coalesced float4 loads (fm is read from HBM exactly once, vs the
// previous version's 7.5x over-fetch from scattered L1/L2 gathers replicated
// across 8 XCD L2s). Then all 98*256 sample points gather their 4 bilinear
// taps from LDS, where 64-lane scatter costs ~6-11 cyc/instr instead of the
// ~60 cyc/instr line-granular L1 path.

#define NN 16
#define CC 128
#define HH 112
#define WW 112
#define PP 98
#define PTS 256                 // 16x16 sample points per patch
#define NPTS (PP * PTS)         // 25088 points per batch image
#define HWs (HH * WW)           // 12544 floats = 49 KB plane
#define THREADS 512             // 50 KB LDS -> 3 blocks/CU -> 24 waves/CU

__global__ __launch_bounds__(THREADS) void patches_kernel(
    const float* __restrict__ fm,
    const float* __restrict__ grid,
    float* __restrict__ out) {
  __shared__ float plane[HWs];

  const int c = blockIdx.x;   // channel
  const int n = blockIdx.y;   // batch
  const int t = threadIdx.x;

  // ---- stage the (n,c) plane into LDS, coalesced float4 (plane is 16B-aligned:
  // 12544 floats = 50176 B per plane, offset multiple of 16) ----
  const float4* __restrict__ src =
      reinterpret_cast<const float4*>(fm + ((size_t)n * CC + c) * HWs);
  float4* dst = reinterpret_cast<float4*>(plane);
#pragma unroll
  for (int i = t; i < HWs / 4; i += THREADS) dst[i] = src[i];
  __syncthreads();

  const float2* __restrict__ g =
      reinterpret_cast<const float2*>(grid) + (size_t)n * NPTS;
  // out element (n,p,c,s) = out[((n*PP+p)*CC + c)*PTS + s]
  float* __restrict__ ob = out + ((size_t)n * PP * CC + c) * PTS;

  // 25088 / 512 = 49 iterations exactly, no remainder
#pragma unroll 7
  for (int pt = t; pt < NPTS; pt += THREADS) {
    const float2 gg = g[pt];

    // unnormalize (align_corners=False) then clamp to border
    float x = fminf(fmaxf(fmaf(gg.x, (float)WW * 0.5f, (float)WW * 0.5f - 0.5f),
                          0.0f), (float)(WW - 1));
    float y = fminf(fmaxf(fmaf(gg.y, (float)HH * 0.5f, (float)HH * 0.5f - 0.5f),
                          0.0f), (float)(HH - 1));

    const float x0f = floorf(x), y0f = floorf(y);
    const float wx = x - x0f, wy = y - y0f;
    const int x0 = (int)x0f;
    const int y0 = (int)y0f;
    const int x1 = min(x0 + 1, WW - 1);
    const int y1 = min(y0 + 1, HH - 1);

    const float w00 = (1.0f - wy) * (1.0f - wx);
    const float w01 = (1.0f - wy) * wx;
    const float w10 = wy * (1.0f - wx);
    const float w11 = wy * wx;

    // 4-tap gather from LDS (random banks; 2-5-way conflicts are cheap)
    float v = plane[y0 * WW + x0] * w00;
    v = fmaf(plane[y0 * WW + x1], w01, v);
    v = fmaf(plane[y1 * WW + x0], w10, v);
    v = fmaf(plane[y1 * WW + x1], w11, v);

    const int p = pt >> 8;      // patch
    const int s = pt & 255;     // sample within patch
    // streaming output, never re-read: bypass L2 so fm/grid keep the cache
    __builtin_nontemporal_store(v, &ob[(size_t)p * CC * PTS + s]);
  }
}

extern "C" void kernel_launch(void* const* d_in, const int* in_sizes, int n_in,
                              void* d_out, int out_size, void* d_ws, size_t ws_size,
                              hipStream_t stream) {
  const float* fm = (const float*)d_in[0];
  const float* grid = (const float*)d_in[1];
  float* out = (float*)d_out;

  dim3 grd(CC, NN);   // 2048 blocks: one (n, c) plane each
  dim3 blk(THREADS);
  patches_kernel<<<grd, blk, 0, stream>>>(fm, grid, out);
}